// Round 1
// baseline (101.140 us; speedup 1.0000x reference)
//
#include <hip/hip_runtime.h>
#include <math.h>

#define INDIM 64
#define HID 32

// Build segment start offsets from the sorted batch array.
// off[b] = first index i with batch[i] >= b ; off[nseg] = n.
__global__ void seg_offsets_kernel(const int* __restrict__ batch, int n, int nseg,
                                   int* __restrict__ off) {
    int i = blockIdx.x * blockDim.x + threadIdx.x;
    if (i >= n) return;
    int cur = batch[i];
    int prev = (i == 0) ? -1 : batch[i - 1];
    for (int b = prev + 1; b <= cur; ++b) off[b] = i;
    if (i == n - 1) {
        for (int b = cur + 1; b <= nseg; ++b) off[b] = n;
    }
}

// One block per segment. 256 threads. Online softmax over chunks of 256 rows.
__global__ __launch_bounds__(256) void fused_seg_attn_kernel(
    const float* __restrict__ x,
    const int* __restrict__ off,
    const float* __restrict__ Wg1, const float* __restrict__ bg1,
    const float* __restrict__ Wg2, const float* __restrict__ bg2,
    const float* __restrict__ Wm1, const float* __restrict__ bm1,
    const float* __restrict__ Wm2, const float* __restrict__ bm2,
    float* __restrict__ out)
{
    __shared__ float4 wg1s[INDIM][HID / 4];   // 8 KB, [k][h4]
    __shared__ float  wg2s[HID];
    __shared__ float  bg1s[HID];
    __shared__ float  wbuf[256];
    __shared__ float  accp[4][INDIM];
    __shared__ float  hg[INDIM];
    __shared__ float  redmax[4];
    __shared__ float  redsum[4];

    const int tid = threadIdx.x;
    const int b   = blockIdx.x;

    // stage gate weights (coalesced float4)
    for (int i = tid; i < INDIM * (HID / 4); i += 256)
        ((float4*)wg1s)[i] = ((const float4*)Wg1)[i];
    if (tid < HID) { wg2s[tid] = Wg2[tid]; bg1s[tid] = bg1[tid]; }
    if (tid < INDIM) hg[tid] = 0.f;

    const int s0 = off[b];
    const int s1 = off[b + 1];
    const float bg2v = bg2[0];
    __syncthreads();

    float m    = -INFINITY;  // running max (redundant per thread)
    float ssum = 0.f;        // running exp-sum

    for (int base = s0; base < s1; base += 256) {
        const int r = base + tid;
        const bool active = (r < s1);
        float g = -INFINITY;
        if (active) {
            // gate MLP for this row: h = relu(x_row @ Wg1 + bg1); g = h @ Wg2 + bg2
            float2 acc[HID / 2];
            #pragma unroll
            for (int j = 0; j < HID / 2; ++j)
                acc[j] = make_float2(bg1s[2 * j], bg1s[2 * j + 1]);
            const float4* xrow = reinterpret_cast<const float4*>(x + (size_t)r * INDIM);
            #pragma unroll
            for (int k4 = 0; k4 < INDIM / 4; ++k4) {
                const float4 xv = xrow[k4];
                #pragma unroll
                for (int kk = 0; kk < 4; ++kk) {
                    const float xk = (kk == 0) ? xv.x : (kk == 1) ? xv.y
                                   : (kk == 2) ? xv.z : xv.w;
                    const int k = k4 * 4 + kk;
                    #pragma unroll
                    for (int j = 0; j < HID / 4; ++j) {
                        const float4 w = wg1s[k][j];   // all-lane broadcast from LDS
                        acc[2 * j].x     = fmaf(xk, w.x, acc[2 * j].x);
                        acc[2 * j].y     = fmaf(xk, w.y, acc[2 * j].y);
                        acc[2 * j + 1].x = fmaf(xk, w.z, acc[2 * j + 1].x);
                        acc[2 * j + 1].y = fmaf(xk, w.w, acc[2 * j + 1].y);
                    }
                }
            }
            float gs = 0.f;
            #pragma unroll
            for (int j = 0; j < HID / 2; ++j) {
                gs = fmaf(fmaxf(acc[j].x, 0.f), wg2s[2 * j],     gs);
                gs = fmaf(fmaxf(acc[j].y, 0.f), wg2s[2 * j + 1], gs);
            }
            g = gs + bg2v;
        }

        // block-wide max of g
        float wm = g;
        #pragma unroll
        for (int d = 1; d < 64; d <<= 1) wm = fmaxf(wm, __shfl_xor(wm, d));
        if ((tid & 63) == 0) redmax[tid >> 6] = wm;
        __syncthreads();
        const float cmax = fmaxf(fmaxf(redmax[0], redmax[1]), fmaxf(redmax[2], redmax[3]));
        const float newm = fmaxf(m, cmax);

        const float w = active ? __expf(g - newm) : 0.f;
        wbuf[tid] = w;
        float wsum = w;
        #pragma unroll
        for (int d = 1; d < 64; d <<= 1) wsum += __shfl_xor(wsum, d);
        if ((tid & 63) == 0) redsum[tid >> 6] = wsum;
        __syncthreads();
        const float csum = (redsum[0] + redsum[1]) + (redsum[2] + redsum[3]);
        const float factor = __expf(m - newm);   // exp(-inf)=0 on first chunk
        ssum = ssum * factor + csum;
        m = newm;

        // weighted accumulation: lane k of wave rg sums w[r]*x[r][k] over its 64 rows
        const int k  = tid & 63;
        const int rg = tid >> 6;
        const int rbase = base + rg * 64;
        int cnt = s1 - rbase; if (cnt > 64) cnt = 64; if (cnt < 0) cnt = 0;
        float pacc = 0.f;
        const float* wsrc = &wbuf[rg * 64];          // wave-uniform -> LDS broadcast
        const float* xcol = x + (size_t)rbase * INDIM + k;  // coalesced, L1/L2-hot
        for (int j = 0; j < cnt; ++j)
            pacc = fmaf(wsrc[j], xcol[(size_t)j * INDIM], pacc);
        accp[rg][k] = pacc;
        __syncthreads();
        if (tid < INDIM)
            hg[tid] = hg[tid] * factor +
                      ((accp[0][tid] + accp[1][tid]) + (accp[2][tid] + accp[3][tid]));
        __syncthreads();  // protect wbuf/red* before next chunk
    }

    // normalize hg
    if (tid < INDIM) {
        const float inv = (ssum > 0.f) ? (1.f / ssum) : 0.f;  // empty segment -> hg = 0
        hg[tid] *= inv;
    }
    __syncthreads();

    // final MLP on wave 0: logit = relu(hg @ Wm1 + bm1) @ Wm2 + bm2
    if (tid < 64) {
        const int h = tid & 31;       // lanes 32..63 duplicate lanes 0..31
        float a = bm1[h];
        #pragma unroll
        for (int k = 0; k < INDIM; ++k)
            a = fmaf(hg[k], Wm1[k * HID + h], a);
        float v = fmaxf(a, 0.f) * Wm2[h];
        #pragma unroll
        for (int d = 1; d < 32; d <<= 1) v += __shfl_xor(v, d);
        if (tid == 0) out[b] = v + bm2[0];
    }
}

extern "C" void kernel_launch(void* const* d_in, const int* in_sizes, int n_in,
                              void* d_out, int out_size, void* d_ws, size_t ws_size,
                              hipStream_t stream) {
    const float* x     = (const float*)d_in[0];
    const int*   batch = (const int*)d_in[1];
    const float* Wg1   = (const float*)d_in[2];
    const float* bg1   = (const float*)d_in[3];
    const float* Wg2   = (const float*)d_in[4];
    const float* bg2   = (const float*)d_in[5];
    const float* Wm1   = (const float*)d_in[6];
    const float* bm1   = (const float*)d_in[7];
    const float* Wm2   = (const float*)d_in[8];
    const float* bm2   = (const float*)d_in[9];
    float* out = (float*)d_out;

    const int n    = in_sizes[1];   // 819200 points
    const int nseg = out_size;      // 4096 segments

    int* off = (int*)d_ws;          // (nseg+1) ints of scratch
    seg_offsets_kernel<<<(n + 255) / 256, 256, 0, stream>>>(batch, n, nseg, off);
    fused_seg_attn_kernel<<<nseg, 256, 0, stream>>>(
        x, off, Wg1, bg1, Wg2, bg2, Wm1, bm1, Wm2, bm2, out);
}